// Round 10
// baseline (40.423 us; speedup 1.0000x reference)
//
#include <hip/hip_runtime.h>
#include <math.h>

#define NPTS   2048
#define BATCH  32
#define M_POLY 815
#define NSPLIT 32            // 2048 / 64, one 64-point group per block
#define QSTR   160           // Q words per point row (5 x 32-word frames)
#define T0OFF  10240         // 64*160; T0col[16][64] lives here (+1024 words)
#define BN_EPS 1e-5f

// chunk ci -> (L=e1+e2, k0=e2 block start, c=e0, qoff4=word offset of Q quad)
// ordering: L-major, then k0-block, then c => wave-mates share the quad addr.
__device__ __forceinline__ bool decode_chunk(int ci, int& Lo, int& k0o, int& co, int& qo) {
    int idx = 0, qoff = 0;
    for (int l = 0; l < 16; ++l) {
        const int nb   = (l + 4) >> 2;
        const int cmin = (l == 0) ? 1 : 0;
        const int nc   = 16 - l - cmin;
        for (int kb = 0; kb < nb; ++kb) {
            if (ci < idx + nc) {
                Lo = l; k0o = kb * 4; co = cmin + (ci - idx);
                qo = qoff + kb * 4;
                return true;
            }
            idx += nc;
        }
        qoff += nb * 4;
    }
    return false;
}

// ---------------------------------------------------------------------------
// Moments kernel. grid (NSPLIT=32, BATCH), block 256, 3 blocks/CU (45 KB LDS).
// One 64-point group per block (GPB=1): more co-resident blocks per CU so
// one block's phase-B LDS read bursts overlap another's phase-A VALU/writes.
// Phase A: build swizzled Q rows (T1*T2 anti-diagonals) + rotated T0col.
// Phase B: per thread (one 4-chunk of monomials), per 4 points:
//          1 b128 T0col quad + 4 b128 Q quads.
// ---------------------------------------------------------------------------
__global__ __launch_bounds__(256) void moments_kernel(
    const float* __restrict__ x,      // (B, 3, N)
    float*       __restrict__ part)   // (B, NSPLIT, M_POLY)
{
    __shared__ __align__(16) float P[64 * QSTR + 1024];   // 45,056 B
    const int t  = threadIdx.x;
    const int sb = blockIdx.x;
    const int b  = blockIdx.y;
    const int nn = t & 63;
    const int qq = t >> 6;
    const int sw = 4 * (nn & 7);
    const int base = nn * QSTR;

    int L, k0, c, qoff4;
    decode_chunk(t, L, k0, c, qoff4);
    // leftover chunks 256..258 = (L=15, c=0, k0=4/8/12) on lanes 253..255
    const bool dual = (t >= 253);
    const int k02   = dual ? 4 * (t - 252) : 4;
    const int qoff42 = 144 + k02;            // Qoff(L=15)=144

    int qx[8], q2x[8];
    #pragma unroll
    for (int r = 0; r < 8; ++r) {
        qx[r]  = qoff4  ^ (4 * r);
        q2x[r] = qoff42 ^ (4 * r);
    }

    float a[4]  = {0.f, 0.f, 0.f, 0.f};
    float a2[4] = {0.f, 0.f, 0.f, 0.f};
    const float* xb = x + (size_t)b * 3 * NPTS;

    {   // ---------------- phase A ----------------
        const int n = sb * 64 + nn;
        const float x1 = xb[NPTS + n], x2 = xb[2 * NPTS + n];
        float T1r[16], T2r[16];
        T1r[0] = 1.f; T1r[1] = x1;
        #pragma unroll
        for (int k = 2; k < 16; ++k) T1r[k] = 2.f * x1 * T1r[k-1] - T1r[k-2];
        T2r[0] = 1.f; T2r[1] = x2;
        #pragma unroll
        for (int k = 2; k < 16; ++k) T2r[k] = 2.f * x2 * T2r[k-1] - T2r[k-2];

        #define QVAL(SS,E) (((E) <= (SS)) ? T1r[((SS)-(E)) & 15] * T2r[(E) & 15] : 0.f)
        #define ROWQ(SS, QO) { \
            _Pragma("unroll") \
            for (int blk2 = 0; blk2 < ((SS)+4)/4; ++blk2) { \
                float4 v; \
                v.x = QVAL(SS, 4*blk2+0); v.y = QVAL(SS, 4*blk2+1); \
                v.z = QVAL(SS, 4*blk2+2); v.w = QVAL(SS, 4*blk2+3); \
                *(float4*)&P[base + (((QO) + 4*blk2) ^ sw)] = v; } }

        if (qq == 0) {
            const float x0 = xb[n];
            float T0r[16];
            T0r[0] = 1.f; T0r[1] = x0;
            #pragma unroll
            for (int k = 2; k < 16; ++k) T0r[k] = 2.f * x0 * T0r[k-1] - T0r[k-2];
            #pragma unroll
            for (int cc = 0; cc < 16; ++cc)
                P[T0OFF + cc * 64 + ((nn + 4 * cc) & 63)] = T0r[cc];
            ROWQ(0, 0)  ROWQ(1, 4)  ROWQ(2, 8)  ROWQ(3, 12)
        } else if (qq == 1) {
            ROWQ(4, 16) ROWQ(5, 24) ROWQ(6, 32) ROWQ(7, 40) ROWQ(8, 48)
        } else if (qq == 2) {
            ROWQ(9, 60) ROWQ(10, 72) ROWQ(11, 84) ROWQ(12, 96)
        } else {
            ROWQ(13, 112) ROWQ(14, 128) ROWQ(15, 144)
        }
        #undef ROWQ
        #undef QVAL
    }
    __syncthreads();

    // ---------------- phase B ----------------
    #pragma unroll 4
    for (int q4 = 0; q4 < 16; ++q4) {
        const int np0 = q4 * 4;
        const float4 t0q =
            *(const float4*)&P[T0OFF + c * 64 + ((np0 + 4 * c) & 63)];
        #pragma unroll
        for (int i = 0; i < 4; ++i) {
            const int np = np0 + i;
            const float* rp = &P[np * QSTR];
            const float  t0v = ((const float*)&t0q)[i];
            const float4 qv = *(const float4*)&rp[qx[np & 7]];
            a[0] = fmaf(t0v, qv.x, a[0]);
            a[1] = fmaf(t0v, qv.y, a[1]);
            a[2] = fmaf(t0v, qv.z, a[2]);
            a[3] = fmaf(t0v, qv.w, a[3]);
            if (dual) {           // e0=0 -> T0 = 1, Q-only accumulate
                const float4 p2 = *(const float4*)&rp[q2x[np & 7]];
                a2[0] += p2.x; a2[1] += p2.y; a2[2] += p2.z; a2[3] += p2.w;
            }
        }
    }

    // store: m = tet(D)-1 + L(L+1)/2 + e2, consecutive in e2
    float* pb = part + ((size_t)b * NSPLIT + sb) * M_POLY;
    {
        const int D  = c + L;
        const int mb = D * (D + 1) * (D + 2) / 6 - 1 + L * (L + 1) / 2;
        const int nv = (L - k0 + 1 < 4) ? (L - k0 + 1) : 4;
        #pragma unroll
        for (int i = 0; i < 4; ++i)
            if (i < nv) pb[mb + k0 + i] = a[i];
    }
    if (dual) {
        const int mb = 799;          // D=15, L=15 base
        #pragma unroll
        for (int i = 0; i < 4; ++i)
            pb[mb + k02 + i] = a2[i];
    }
}

// ---------------------------------------------------------------------------
// Layer 1: reduce 32 partials + 815->512 + BN + ReLU.
// grid = (8, 32), block 512 = 64 outputs x 8 k-groups (chains of 102).
// ---------------------------------------------------------------------------
__global__ __launch_bounds__(512) void l1_kernel(
    const float* __restrict__ part,
    const float* __restrict__ W1, const float* __restrict__ b1,
    const float* __restrict__ g1, const float* __restrict__ be1,
    const float* __restrict__ rm1, const float* __restrict__ rv1,
    float* __restrict__ h1)
{
    __shared__ float fs[816];
    __shared__ float red[8][64];
    const int t  = threadIdx.x;
    const int og = blockIdx.x;
    const int b  = blockIdx.y;

    {
        float s0 = 0.f;
        #pragma unroll 8
        for (int sp = 0; sp < NSPLIT; ++sp)
            s0 += part[((size_t)b * NSPLIT + sp) * M_POLY + t];
        fs[t] = s0 * (1.0f / (float)NPTS);
        if (t < 303) {
            float s1 = 0.f;
            #pragma unroll 8
            for (int sp = 0; sp < NSPLIT; ++sp)
                s1 += part[((size_t)b * NSPLIT + sp) * M_POLY + 512 + t];
            fs[512 + t] = s1 * (1.0f / (float)NPTS);
        }
        if (t == 0) fs[815] = 0.f;
    }
    __syncthreads();

    const int o  = og * 64 + (t & 63);
    const int cg = t >> 6;
    const int kb = cg * 102;               // 8*102 = 816; fs[815]=0 nulls pad
    float acc = 0.f;
    #pragma unroll 6
    for (int kk = 0; kk < 102; ++kk) {
        const int k  = kb + kk;
        const int kr = (k < 815) ? k : 814;
        acc = fmaf(fs[k], W1[(size_t)kr * 512 + o], acc);
    }
    red[cg][t & 63] = acc;
    __syncthreads();

    if (t < 64) {
        float dot = 0.f;
        #pragma unroll
        for (int j = 0; j < 8; ++j) dot += red[j][t];
        const int oo = og * 64 + t;
        const float v = (dot + b1[oo] - rm1[oo]) * g1[oo] * rsqrtf(rv1[oo] + BN_EPS) + be1[oo];
        h1[b * 512 + oo] = v > 0.f ? v : 0.f;
    }
}

// ---------------------------------------------------------------------------
// Layer 2 — byte-identical to R9. grid (8, 32), block 512 = 32 o x 16 kg.
// ---------------------------------------------------------------------------
__global__ __launch_bounds__(512) void l2_kernel(
    const float* __restrict__ h1,
    const float* __restrict__ W2, const float* __restrict__ b2,
    const float* __restrict__ g2, const float* __restrict__ be2,
    const float* __restrict__ rm2, const float* __restrict__ rv2,
    float* __restrict__ h2)
{
    __shared__ float hs[512];
    __shared__ float red[16][32];
    const int t  = threadIdx.x;
    const int og = blockIdx.x;
    const int b  = blockIdx.y;

    hs[t] = h1[b * 512 + t];
    __syncthreads();

    const int o  = og * 32 + (t & 31);
    const int cg = t >> 5;
    const int kb = cg * 32;
    float acc = 0.f;
    #pragma unroll
    for (int kk = 0; kk < 32; ++kk)
        acc = fmaf(hs[kb + kk], W2[(size_t)(kb + kk) * 256 + o], acc);
    red[cg][t & 31] = acc;
    __syncthreads();

    if (t < 32) {
        float dot = 0.f;
        #pragma unroll
        for (int j = 0; j < 16; ++j) dot += red[j][t];
        const int oo = og * 32 + t;
        const float v = (dot + b2[oo] - rm2[oo]) * g2[oo] * rsqrtf(rv2[oo] + BN_EPS) + be2[oo];
        h2[b * 256 + oo] = v > 0.f ? v : 0.f;
    }
}

// ---------------------------------------------------------------------------
// Layers 3+4 — byte-identical to R9. grid = 32, block 512.
// ---------------------------------------------------------------------------
__global__ __launch_bounds__(512) void l34_kernel(
    const float* __restrict__ h2,
    const float* __restrict__ W3, const float* __restrict__ b3,
    const float* __restrict__ g3, const float* __restrict__ be3,
    const float* __restrict__ rm3, const float* __restrict__ rv3,
    const float* __restrict__ W4, const float* __restrict__ b4,
    float* __restrict__ out)
{
    __shared__ float hs[256];
    __shared__ float red3[4][128];
    __shared__ float h3s[128];
    __shared__ float red4[8][64];
    const int t = threadIdx.x;
    const int b = blockIdx.x;

    if (t < 256) hs[t] = h2[b * 256 + t];
    __syncthreads();

    {
        const int o  = t & 127;
        const int cg = t >> 7;
        const int kb = cg * 64;
        float acc = 0.f;
        #pragma unroll 8
        for (int kk = 0; kk < 64; ++kk)
            acc = fmaf(hs[kb + kk], W3[(size_t)(kb + kk) * 128 + o], acc);
        red3[cg][o] = acc;
    }
    __syncthreads();
    if (t < 128) {
        const float dot = red3[0][t] + red3[1][t] + red3[2][t] + red3[3][t];
        const float v = (dot + b3[t] - rm3[t]) * g3[t] * rsqrtf(rv3[t] + BN_EPS) + be3[t];
        h3s[t] = v > 0.f ? v : 0.f;
    }
    __syncthreads();

    {
        const int o  = t & 63;
        const int om = (o < 40) ? o : 39;
        const int cg = t >> 6;
        const int kb = cg * 16;
        float acc = 0.f;
        #pragma unroll
        for (int kk = 0; kk < 16; ++kk)
            acc = fmaf(h3s[kb + kk], W4[(size_t)(kb + kk) * 40 + om], acc);
        red4[cg][o] = acc;
    }
    __syncthreads();
    if (t < 40) {
        float dot = 0.f;
        #pragma unroll
        for (int j = 0; j < 8; ++j) dot += red4[j][t];
        out[b * 40 + t] = dot + b4[t];
    }
}

extern "C" void kernel_launch(void* const* d_in, const int* in_sizes, int n_in,
                              void* d_out, int out_size, void* d_ws, size_t ws_size,
                              hipStream_t stream) {
    const float* x  = (const float*)d_in[0];
    const float* W1 = (const float*)d_in[2];
    const float* b1 = (const float*)d_in[3];
    const float* g1 = (const float*)d_in[4];
    const float* be1= (const float*)d_in[5];
    const float* rm1= (const float*)d_in[6];
    const float* rv1= (const float*)d_in[7];
    const float* W2 = (const float*)d_in[8];
    const float* b2 = (const float*)d_in[9];
    const float* g2 = (const float*)d_in[10];
    const float* be2= (const float*)d_in[11];
    const float* rm2= (const float*)d_in[12];
    const float* rv2= (const float*)d_in[13];
    const float* W3 = (const float*)d_in[14];
    const float* b3 = (const float*)d_in[15];
    const float* g3 = (const float*)d_in[16];
    const float* be3= (const float*)d_in[17];
    const float* rm3= (const float*)d_in[18];
    const float* rv3= (const float*)d_in[19];
    const float* W4 = (const float*)d_in[20];
    const float* b4 = (const float*)d_in[21];
    float* out = (float*)d_out;

    float* part = (float*)d_ws;                              // 32*32*815 f32
    float* h1   = part + (size_t)BATCH * NSPLIT * M_POLY;    // 32*512
    float* h2   = h1 + (size_t)BATCH * 512;                  // 32*256

    moments_kernel<<<dim3(NSPLIT, BATCH), 256, 0, stream>>>(x, part);
    l1_kernel<<<dim3(8, BATCH), 512, 0, stream>>>(part,
        W1, b1, g1, be1, rm1, rv1, h1);
    l2_kernel<<<dim3(8, BATCH), 512, 0, stream>>>(h1,
        W2, b2, g2, be2, rm2, rv2, h2);
    l34_kernel<<<BATCH, 512, 0, stream>>>(h2,
        W3, b3, g3, be3, rm3, rv3, W4, b4, out);
}

// Round 11
// 31.909 us; speedup vs baseline: 1.2668x; 1.2668x over previous
//
#include <hip/hip_runtime.h>
#include <math.h>

#define NPTS   2048
#define BATCH  32
#define M_POLY 815
#define GPB    2
#define NSPLIT 16            // 2048 / (64*GPB)
#define QSTR   160           // Q words per point row (5 x 32-word frames)
#define T0OFF  10240         // 64*160; T0col[16][64] lives here (+1024 words)
#define BN_EPS 1e-5f

// chunk ci -> (L=e1+e2, k0=e2 block start, c=e0, qoff4=word offset of Q quad)
// ordering: L-major, then k0-block, then c => wave-mates share the quad addr.
__device__ __forceinline__ bool decode_chunk(int ci, int& Lo, int& k0o, int& co, int& qo) {
    int idx = 0, qoff = 0;
    for (int l = 0; l < 16; ++l) {
        const int nb   = (l + 4) >> 2;
        const int cmin = (l == 0) ? 1 : 0;
        const int nc   = 16 - l - cmin;
        for (int kb = 0; kb < nb; ++kb) {
            if (ci < idx + nc) {
                Lo = l; k0o = kb * 4; co = cmin + (ci - idx);
                qo = qoff + kb * 4;
                return true;
            }
            idx += nc;
        }
        qoff += nb * 4;
    }
    return false;
}

// ---------------------------------------------------------------------------
// Moments kernel — R9 structure (measured best 32.0 µs): grid (16, 32),
// block 256, GPB=2, 2 blocks/CU (45 KB LDS). Only change vs R9: phase-B
// unroll 4 -> 8 for deeper ds_read_b128 pipelining.
// ---------------------------------------------------------------------------
__global__ __launch_bounds__(256) void moments_kernel(
    const float* __restrict__ x,      // (B, 3, N)
    float*       __restrict__ part)   // (B, NSPLIT, M_POLY)
{
    __shared__ __align__(16) float P[64 * QSTR + 1024];   // 45,056 B
    const int t  = threadIdx.x;
    const int sb = blockIdx.x;
    const int b  = blockIdx.y;
    const int nn = t & 63;
    const int qq = t >> 6;
    const int sw = 4 * (nn & 7);
    const int base = nn * QSTR;

    int L, k0, c, qoff4;
    decode_chunk(t, L, k0, c, qoff4);
    // leftover chunks 256..258 = (L=15, c=0, k0=4/8/12) on lanes 253..255
    const bool dual = (t >= 253);
    const int k02   = dual ? 4 * (t - 252) : 4;
    const int qoff42 = 144 + k02;            // Qoff(L=15)=144

    int qx[8], q2x[8];
    #pragma unroll
    for (int r = 0; r < 8; ++r) {
        qx[r]  = qoff4  ^ (4 * r);
        q2x[r] = qoff42 ^ (4 * r);
    }

    float a[4]  = {0.f, 0.f, 0.f, 0.f};
    float a2[4] = {0.f, 0.f, 0.f, 0.f};
    const float* xb = x + (size_t)b * 3 * NPTS;

    for (int g = 0; g < GPB; ++g) {
        if (g) __syncthreads();
        {   // ---------------- phase A ----------------
            const int n = (sb * GPB + g) * 64 + nn;
            const float x1 = xb[NPTS + n], x2 = xb[2 * NPTS + n];
            float T1r[16], T2r[16];
            T1r[0] = 1.f; T1r[1] = x1;
            #pragma unroll
            for (int k = 2; k < 16; ++k) T1r[k] = 2.f * x1 * T1r[k-1] - T1r[k-2];
            T2r[0] = 1.f; T2r[1] = x2;
            #pragma unroll
            for (int k = 2; k < 16; ++k) T2r[k] = 2.f * x2 * T2r[k-1] - T2r[k-2];

            #define QVAL(SS,E) (((E) <= (SS)) ? T1r[((SS)-(E)) & 15] * T2r[(E) & 15] : 0.f)
            #define ROWQ(SS, QO) { \
                _Pragma("unroll") \
                for (int blk2 = 0; blk2 < ((SS)+4)/4; ++blk2) { \
                    float4 v; \
                    v.x = QVAL(SS, 4*blk2+0); v.y = QVAL(SS, 4*blk2+1); \
                    v.z = QVAL(SS, 4*blk2+2); v.w = QVAL(SS, 4*blk2+3); \
                    *(float4*)&P[base + (((QO) + 4*blk2) ^ sw)] = v; } }

            if (qq == 0) {
                const float x0 = xb[n];
                float T0r[16];
                T0r[0] = 1.f; T0r[1] = x0;
                #pragma unroll
                for (int k = 2; k < 16; ++k) T0r[k] = 2.f * x0 * T0r[k-1] - T0r[k-2];
                #pragma unroll
                for (int cc = 0; cc < 16; ++cc)
                    P[T0OFF + cc * 64 + ((nn + 4 * cc) & 63)] = T0r[cc];
                ROWQ(0, 0)  ROWQ(1, 4)  ROWQ(2, 8)  ROWQ(3, 12)
            } else if (qq == 1) {
                ROWQ(4, 16) ROWQ(5, 24) ROWQ(6, 32) ROWQ(7, 40) ROWQ(8, 48)
            } else if (qq == 2) {
                ROWQ(9, 60) ROWQ(10, 72) ROWQ(11, 84) ROWQ(12, 96)
            } else {
                ROWQ(13, 112) ROWQ(14, 128) ROWQ(15, 144)
            }
            #undef ROWQ
            #undef QVAL
        }
        __syncthreads();

        // ---------------- phase B ----------------
        #pragma unroll 8
        for (int q4 = 0; q4 < 16; ++q4) {
            const int np0 = q4 * 4;
            const float4 t0q =
                *(const float4*)&P[T0OFF + c * 64 + ((np0 + 4 * c) & 63)];
            #pragma unroll
            for (int i = 0; i < 4; ++i) {
                const int np = np0 + i;
                const float* rp = &P[np * QSTR];
                const float  t0v = ((const float*)&t0q)[i];
                const float4 qv = *(const float4*)&rp[qx[np & 7]];
                a[0] = fmaf(t0v, qv.x, a[0]);
                a[1] = fmaf(t0v, qv.y, a[1]);
                a[2] = fmaf(t0v, qv.z, a[2]);
                a[3] = fmaf(t0v, qv.w, a[3]);
                if (dual) {           // e0=0 -> T0 = 1, Q-only accumulate
                    const float4 p2 = *(const float4*)&rp[q2x[np & 7]];
                    a2[0] += p2.x; a2[1] += p2.y; a2[2] += p2.z; a2[3] += p2.w;
                }
            }
        }
    }

    // store: m = tet(D)-1 + L(L+1)/2 + e2, consecutive in e2
    float* pb = part + ((size_t)b * NSPLIT + sb) * M_POLY;
    {
        const int D  = c + L;
        const int mb = D * (D + 1) * (D + 2) / 6 - 1 + L * (L + 1) / 2;
        const int nv = (L - k0 + 1 < 4) ? (L - k0 + 1) : 4;
        #pragma unroll
        for (int i = 0; i < 4; ++i)
            if (i < nv) pb[mb + k0 + i] = a[i];
    }
    if (dual) {
        const int mb = 799;          // D=15, L=15 base
        #pragma unroll
        for (int i = 0; i < 4; ++i)
            pb[mb + k02 + i] = a2[i];
    }
}

// ---------------------------------------------------------------------------
// Layer 1 — byte-identical to R9. grid (8, 32), block 512 = 64 o x 8 kg.
// ---------------------------------------------------------------------------
__global__ __launch_bounds__(512) void l1_kernel(
    const float* __restrict__ part,
    const float* __restrict__ W1, const float* __restrict__ b1,
    const float* __restrict__ g1, const float* __restrict__ be1,
    const float* __restrict__ rm1, const float* __restrict__ rv1,
    float* __restrict__ h1)
{
    __shared__ float fs[816];
    __shared__ float red[8][64];
    const int t  = threadIdx.x;
    const int og = blockIdx.x;
    const int b  = blockIdx.y;

    {
        float s0 = 0.f;
        #pragma unroll
        for (int sp = 0; sp < NSPLIT; ++sp)
            s0 += part[((size_t)b * NSPLIT + sp) * M_POLY + t];
        fs[t] = s0 * (1.0f / (float)NPTS);
        if (t < 303) {
            float s1 = 0.f;
            #pragma unroll
            for (int sp = 0; sp < NSPLIT; ++sp)
                s1 += part[((size_t)b * NSPLIT + sp) * M_POLY + 512 + t];
            fs[512 + t] = s1 * (1.0f / (float)NPTS);
        }
        if (t == 0) fs[815] = 0.f;
    }
    __syncthreads();

    const int o  = og * 64 + (t & 63);
    const int cg = t >> 6;
    const int kb = cg * 102;               // 8*102 = 816; fs[815]=0 nulls pad
    float acc = 0.f;
    #pragma unroll 6
    for (int kk = 0; kk < 102; ++kk) {
        const int k  = kb + kk;
        const int kr = (k < 815) ? k : 814;
        acc = fmaf(fs[k], W1[(size_t)kr * 512 + o], acc);
    }
    red[cg][t & 63] = acc;
    __syncthreads();

    if (t < 64) {
        float dot = 0.f;
        #pragma unroll
        for (int j = 0; j < 8; ++j) dot += red[j][t];
        const int oo = og * 64 + t;
        const float v = (dot + b1[oo] - rm1[oo]) * g1[oo] * rsqrtf(rv1[oo] + BN_EPS) + be1[oo];
        h1[b * 512 + oo] = v > 0.f ? v : 0.f;
    }
}

// ---------------------------------------------------------------------------
// Layer 2 — byte-identical to R9. grid (8, 32), block 512 = 32 o x 16 kg.
// ---------------------------------------------------------------------------
__global__ __launch_bounds__(512) void l2_kernel(
    const float* __restrict__ h1,
    const float* __restrict__ W2, const float* __restrict__ b2,
    const float* __restrict__ g2, const float* __restrict__ be2,
    const float* __restrict__ rm2, const float* __restrict__ rv2,
    float* __restrict__ h2)
{
    __shared__ float hs[512];
    __shared__ float red[16][32];
    const int t  = threadIdx.x;
    const int og = blockIdx.x;
    const int b  = blockIdx.y;

    hs[t] = h1[b * 512 + t];
    __syncthreads();

    const int o  = og * 32 + (t & 31);
    const int cg = t >> 5;
    const int kb = cg * 32;
    float acc = 0.f;
    #pragma unroll
    for (int kk = 0; kk < 32; ++kk)
        acc = fmaf(hs[kb + kk], W2[(size_t)(kb + kk) * 256 + o], acc);
    red[cg][t & 31] = acc;
    __syncthreads();

    if (t < 32) {
        float dot = 0.f;
        #pragma unroll
        for (int j = 0; j < 16; ++j) dot += red[j][t];
        const int oo = og * 32 + t;
        const float v = (dot + b2[oo] - rm2[oo]) * g2[oo] * rsqrtf(rv2[oo] + BN_EPS) + be2[oo];
        h2[b * 256 + oo] = v > 0.f ? v : 0.f;
    }
}

// ---------------------------------------------------------------------------
// Layers 3+4 — byte-identical to R9. grid = 32, block 512.
// ---------------------------------------------------------------------------
__global__ __launch_bounds__(512) void l34_kernel(
    const float* __restrict__ h2,
    const float* __restrict__ W3, const float* __restrict__ b3,
    const float* __restrict__ g3, const float* __restrict__ be3,
    const float* __restrict__ rm3, const float* __restrict__ rv3,
    const float* __restrict__ W4, const float* __restrict__ b4,
    float* __restrict__ out)
{
    __shared__ float hs[256];
    __shared__ float red3[4][128];
    __shared__ float h3s[128];
    __shared__ float red4[8][64];
    const int t = threadIdx.x;
    const int b = blockIdx.x;

    if (t < 256) hs[t] = h2[b * 256 + t];
    __syncthreads();

    {
        const int o  = t & 127;
        const int cg = t >> 7;
        const int kb = cg * 64;
        float acc = 0.f;
        #pragma unroll 8
        for (int kk = 0; kk < 64; ++kk)
            acc = fmaf(hs[kb + kk], W3[(size_t)(kb + kk) * 128 + o], acc);
        red3[cg][o] = acc;
    }
    __syncthreads();
    if (t < 128) {
        const float dot = red3[0][t] + red3[1][t] + red3[2][t] + red3[3][t];
        const float v = (dot + b3[t] - rm3[t]) * g3[t] * rsqrtf(rv3[t] + BN_EPS) + be3[t];
        h3s[t] = v > 0.f ? v : 0.f;
    }
    __syncthreads();

    {
        const int o  = t & 63;
        const int om = (o < 40) ? o : 39;
        const int cg = t >> 6;
        const int kb = cg * 16;
        float acc = 0.f;
        #pragma unroll
        for (int kk = 0; kk < 16; ++kk)
            acc = fmaf(h3s[kb + kk], W4[(size_t)(kb + kk) * 40 + om], acc);
        red4[cg][o] = acc;
    }
    __syncthreads();
    if (t < 40) {
        float dot = 0.f;
        #pragma unroll
        for (int j = 0; j < 8; ++j) dot += red4[j][t];
        out[b * 40 + t] = dot + b4[t];
    }
}

extern "C" void kernel_launch(void* const* d_in, const int* in_sizes, int n_in,
                              void* d_out, int out_size, void* d_ws, size_t ws_size,
                              hipStream_t stream) {
    const float* x  = (const float*)d_in[0];
    const float* W1 = (const float*)d_in[2];
    const float* b1 = (const float*)d_in[3];
    const float* g1 = (const float*)d_in[4];
    const float* be1= (const float*)d_in[5];
    const float* rm1= (const float*)d_in[6];
    const float* rv1= (const float*)d_in[7];
    const float* W2 = (const float*)d_in[8];
    const float* b2 = (const float*)d_in[9];
    const float* g2 = (const float*)d_in[10];
    const float* be2= (const float*)d_in[11];
    const float* rm2= (const float*)d_in[12];
    const float* rv2= (const float*)d_in[13];
    const float* W3 = (const float*)d_in[14];
    const float* b3 = (const float*)d_in[15];
    const float* g3 = (const float*)d_in[16];
    const float* be3= (const float*)d_in[17];
    const float* rm3= (const float*)d_in[18];
    const float* rv3= (const float*)d_in[19];
    const float* W4 = (const float*)d_in[20];
    const float* b4 = (const float*)d_in[21];
    float* out = (float*)d_out;

    float* part = (float*)d_ws;                              // 32*16*815 f32
    float* h1   = part + (size_t)BATCH * NSPLIT * M_POLY;    // 32*512
    float* h2   = h1 + (size_t)BATCH * 512;                  // 32*256

    moments_kernel<<<dim3(NSPLIT, BATCH), 256, 0, stream>>>(x, part);
    l1_kernel<<<dim3(8, BATCH), 512, 0, stream>>>(part,
        W1, b1, g1, be1, rm1, rv1, h1);
    l2_kernel<<<dim3(8, BATCH), 512, 0, stream>>>(h1,
        W2, b2, g2, be2, rm2, rv2, h2);
    l34_kernel<<<BATCH, 512, 0, stream>>>(h2,
        W3, b3, g3, be3, rm3, rv3, W4, b4, out);
}